// Round 3
// baseline (32.721 us; speedup 1.0000x reference)
//
#include <hip/hip_runtime.h>
#include <math.h>

#define HDIM 128
#define SENT -1e30f
#define DEPTH 8   // rows per half-wave per iteration (loads in flight per lane)

// Wave-parallel lower_bound: smallest idx with seg[idx] >= target, in [0, N].
// Must be called by all 64 lanes of a wave with uniform (N, target).
__device__ __forceinline__ int wave_lower_bound(const int* __restrict__ seg, int N, int target) {
    const int lane = threadIdx.x & 63;
    int lo = 0, hi = N;                       // answer in [lo, hi]
    while (hi - lo > 64) {
        int len = hi - lo;
        int chunk = (len + 63) >> 6;          // >= 2
        int pos = lo + lane * chunk;          // lane 0 probes lo
        int v = (pos < hi) ? seg[pos] : 0x7fffffff;
        unsigned long long bal = __ballot(v < target);
        int cnt = __popcll(bal);              // sorted -> lanes 0..cnt-1 true
        if (cnt == 0) { hi = lo; break; }     // seg[lo] >= target -> answer == lo
        int nlo = lo + (cnt - 1) * chunk + 1; // seg at (cnt-1)*chunk < target
        int nhi = (cnt < 64) ? min(hi, lo + cnt * chunk) : hi;
        lo = nlo; hi = nhi;
    }
    int pos = lo + lane;
    int v = (pos < hi) ? seg[pos] : 0x7fffffff;
    unsigned long long bal = __ballot(v < target);
    return lo + __popcll(bal);
}

__global__ void __launch_bounds__(1024, 4)   // cap VGPR<=128: keep 16 waves/CU
att_pool_kernel(const float* __restrict__ s,      // [B,H]
                const float* __restrict__ x,      // [N,H] node_embeds
                const float* __restrict__ W,      // [H,H]
                const int*   __restrict__ seg,    // [N] sorted
                float*       __restrict__ out,    // [B,H]
                int N, int B)
{
    const int b    = blockIdx.x;
    const int tid  = threadIdx.x;
    const int wave = tid >> 6;        // 0..15
    const int lane = tid & 63;
    const int half = lane >> 5;       // 0 or 1
    const int hl   = lane & 31;       // lane within half: owns channels 4*hl..4*hl+3

    __shared__ float ws_lds[HDIM];
    __shared__ int   se[2];
    __shared__ float lm[32], ll[32];
    __shared__ float lacc[32][HDIM];
    __shared__ float sscale[32];
    __shared__ float sdenom;

    // ---- Preamble (overlapped): waves 0-1 search segment bounds while
    //      waves 2-9 compute ws_b = W @ s_b  (ws[k] = sum_j W[k,j]*s[b,j]) ----
    if (wave == 0) {
        int v = wave_lower_bound(seg, N, b);
        if (lane == 0) se[0] = v;
    } else if (wave == 1) {
        int v = wave_lower_bound(seg, N, b + 1);
        if (lane == 0) se[1] = v;
    } else if (wave < 10) {
        const int k = (wave - 2) * 16 + (lane >> 2);   // 8 waves x 16 rows = 128
        const int g = lane & 3;                        // 4 lanes per k-row
        const float* Wr = W + (size_t)k * HDIM;
        const float* sr = s + (size_t)b * HDIM;
        float partial = 0.f;
        #pragma unroll
        for (int ii = 0; ii < 8; ++ii) {
            int j0 = (g + 4 * ii) * 4;                 // 32 float4 chunks
            float4 wv4 = *reinterpret_cast<const float4*>(Wr + j0);
            float4 sv4 = *reinterpret_cast<const float4*>(sr + j0);
            partial += wv4.x * sv4.x + wv4.y * sv4.y + wv4.z * sv4.z + wv4.w * sv4.w;
        }
        partial += __shfl_xor(partial, 1, 64);
        partial += __shfl_xor(partial, 2, 64);
        if (g == 0) ws_lds[k] = partial;
    }
    __syncthreads();

    const int start = se[0];
    const int end   = se[1];
    const int last  = end - 1;
    const float4 wv = *reinterpret_cast<const float4*>(&ws_lds[4 * hl]);

    // ---- Main: one-pass online softmax + weighted accumulation ----
    // Block covers 256 rows/iter; wave w owns rows p+16w+{0..15}; each 32-lane
    // half owns 8 of them (DEPTH loads in flight per lane for MLP).
    // Loads unconditional (clamped to `last`); invalid rows get e=0.
    float  m = SENT, l = 0.f;
    float4 acc = make_float4(0.f, 0.f, 0.f, 0.f);

    for (int p = start; p < end; p += 16 * DEPTH * 2) {
        const int rb = p + 2 * DEPTH * wave + half;

        float4 xv[DEPTH];
        #pragma unroll
        for (int k = 0; k < DEPTH; ++k) {
            const int c = min(rb + 2 * k, last);
            xv[k] = *reinterpret_cast<const float4*>(x + (size_t)c * HDIM + 4 * hl);
        }

        float h[DEPTH];
        #pragma unroll
        for (int k = 0; k < DEPTH; ++k)
            h[k] = xv[k].x * wv.x + xv[k].y * wv.y + xv[k].z * wv.z + xv[k].w * wv.w;

        #pragma unroll
        for (int off = 16; off >= 1; off >>= 1) {   // reduce within 32-lane half
            #pragma unroll
            for (int k = 0; k < DEPTH; ++k) h[k] += __shfl_xor(h[k], off, 64);
        }

        float mn = m;
        #pragma unroll
        for (int k = 0; k < DEPTH; ++k) {
            h[k] = (rb + 2 * k < end) ? h[k] : SENT;
            mn = fmaxf(mn, h[k]);
        }

        float sc = __expf(m - mn);                  // m==SENT,mn==SENT -> 1, but l==0
        float e[DEPTH];
        float esum = 0.f;
        #pragma unroll
        for (int k = 0; k < DEPTH; ++k) {
            e[k] = (rb + 2 * k < end) ? __expf(h[k] - mn) : 0.f;
            esum += e[k];
        }

        float ax = acc.x * sc, ay = acc.y * sc, az = acc.z * sc, aw = acc.w * sc;
        #pragma unroll
        for (int k = 0; k < DEPTH; ++k) {
            ax += e[k] * xv[k].x;
            ay += e[k] * xv[k].y;
            az += e[k] * xv[k].z;
            aw += e[k] * xv[k].w;
        }
        acc = make_float4(ax, ay, az, aw);
        l = l * sc + esum;
        m = mn;
    }

    // ---- Merge the 32 half-wave online-softmax states ----
    const int st = wave * 2 + half;
    *reinterpret_cast<float4*>(&lacc[st][4 * hl]) = acc;
    if (hl == 0) { lm[st] = m; ll[st] = l; }
    __syncthreads();

    if (wave == 0 && lane < 32) {                   // parallel merge, xor<=16 stays in-half
        float mi = lm[lane], li = ll[lane];
        float M = mi;
        #pragma unroll
        for (int off = 16; off >= 1; off >>= 1) M = fmaxf(M, __shfl_xor(M, off, 64));
        float sc = (li > 0.f) ? __expf(mi - M) : 0.f;
        float d  = li * sc;
        #pragma unroll
        for (int off = 16; off >= 1; off >>= 1) d += __shfl_xor(d, off, 64);
        sscale[lane] = sc;
        if (lane == 0) sdenom = d;
    }
    __syncthreads();

    if (tid < HDIM) {
        float num = 0.f;
        #pragma unroll
        for (int i = 0; i < 32; ++i) num += lacc[i][tid] * sscale[i];
        float D = sdenom;
        out[(size_t)b * HDIM + tid] = (D > 0.f) ? (num / D) : 0.f;  // empty segment -> 0
    }
}

extern "C" void kernel_launch(void* const* d_in, const int* in_sizes, int n_in,
                              void* d_out, int out_size, void* d_ws, size_t ws_size,
                              hipStream_t stream) {
    const float* s   = (const float*)d_in[0];  // [B,H]
    const float* x   = (const float*)d_in[1];  // [N,H]
    const float* W   = (const float*)d_in[2];  // [H,H]
    const int*   seg = (const int*)  d_in[3];  // [N]
    float* out = (float*)d_out;

    const int B = in_sizes[0] / HDIM;
    const int N = in_sizes[3];

    att_pool_kernel<<<B, 1024, 0, stream>>>(s, x, W, seg, out, N, B);
}